// Round 3
// baseline (687.350 us; speedup 1.0000x reference)
//
#include <hip/hip_runtime.h>
#include <hip/hip_bf16.h>

// DKVMN fused pipeline for MI355X (gfx950)
// B=256, T=512, DIM_KEY=256, DIM_VALUE=128, NUM_ITEM=2000
// k0_cvt : f32 tables -> bf16 tables in ws
// k1_wea : gather + [Mk|e_W|a_W] GEMM (bf16 MFMA) + softmax/sigmoid/tanh -> ws
// k2_scan: per-batch scan; M state in VGPRs, 8 waves split v; distance-2
//          prefetch; distributed LDS reduce (no wave-0 serial tail)
// k3_f   : [reads|k] @ f_W^T GEMM (bf16 MFMA) + tanh -> ws (aliases e)
// k4_pred: sigmoid(f . p_W + p_b) -> d_out (f32)

#define T_SEQ 512
#define DK    256
#define DV    128
#define NITEM 2000
#define BT    131072   // 256*512

typedef __attribute__((ext_vector_type(8))) short bf16x8;
typedef __attribute__((ext_vector_type(4))) float f32x4;
typedef __attribute__((ext_vector_type(2))) float f32x2;

__device__ __forceinline__ float bf2f(unsigned short u) {
    return __uint_as_float(((unsigned int)u) << 16);
}
__device__ __forceinline__ unsigned short f2bf(float x) {   // RNE f32->bf16
    unsigned int u = __float_as_uint(x);
    return (unsigned short)((u + 0x7fffu + ((u >> 16) & 1u)) >> 16);
}
__device__ __forceinline__ float fast_rcp(float x) { return __builtin_amdgcn_rcpf(x); }
__device__ __forceinline__ float fast_sigmoid(float x) { return fast_rcp(1.f + __expf(-x)); }
__device__ __forceinline__ float fast_tanh(float x) {
    float t = __expf(2.f * x);
    return (t - 1.f) * fast_rcp(t + 1.f);
}

// 2xf32 fma helper. NOTE (R2 post-mortem): v_pk_fma_f32 is throughput-neutral
// on CDNA4 (157.3 TF peak == scalar fma rate); this exists only for brevity.
__device__ __forceinline__ f32x2 pk_fma(f32x2 a, f32x2 b, f32x2 c) {
#if __has_builtin(__builtin_elementwise_fma)
    return __builtin_elementwise_fma(a, b, c);
#else
    f32x2 d; d.x = fmaf(a.x, b.x, c.x); d.y = fmaf(a.y, b.y, c.y); return d;
#endif
}

// ---------------------------------------------------------------------------
// k0: f32 -> bf16 table conversion (up to 5 tables per launch, y = table id)
// ---------------------------------------------------------------------------
__global__ __launch_bounds__(256) void k0_cvt(
    const float* __restrict__ s0, const float* __restrict__ s1,
    const float* __restrict__ s2, const float* __restrict__ s3,
    const float* __restrict__ s4,
    unsigned short* __restrict__ d0, unsigned short* __restrict__ d1,
    unsigned short* __restrict__ d2, unsigned short* __restrict__ d3,
    unsigned short* __restrict__ d4,
    int n0, int n1, int n2, int n3, int n4)
{
    const float* s; unsigned short* d; int n;
    switch (blockIdx.y) {
        case 0:  s = s0; d = d0; n = n0; break;
        case 1:  s = s1; d = d1; n = n1; break;
        case 2:  s = s2; d = d2; n = n2; break;
        case 3:  s = s3; d = d3; n = n3; break;
        default: s = s4; d = d4; n = n4; break;
    }
    int i4 = (blockIdx.x * 256 + threadIdx.x) * 4;
    if (i4 < n) {
        float4 v = *(const float4*)(s + i4);
        ushort4 o;
        o.x = f2bf(v.x); o.y = f2bf(v.y); o.z = f2bf(v.z); o.w = f2bf(v.w);
        *(ushort4*)(d + i4) = o;
    }
}

// ---------------------------------------------------------------------------
// K1: 128 rows x 128 cols per block, 4 waves stacked by rows.
// ---------------------------------------------------------------------------
__global__ __launch_bounds__(256) void k1_wea(
    const int* __restrict__ item_seq, const int* __restrict__ correct_seq,
    const unsigned short* __restrict__ k_bf, const unsigned short* __restrict__ v_bf,
    const unsigned short* __restrict__ Mk_bf,
    const unsigned short* __restrict__ eW_bf, const float* __restrict__ e_b,
    const unsigned short* __restrict__ aW_bf, const float* __restrict__ a_b,
    unsigned short* __restrict__ Wout, unsigned short* __restrict__ Eout,
    unsigned short* __restrict__ Aout)
{
    const int m_tile = blockIdx.x;   // 0..1023
    const int n_tile = blockIdx.y;   // 0..4
    const int tid  = threadIdx.x;
    const int lane = tid & 63;
    const int wv   = tid >> 6;

    __shared__ int idx_s[128];
    __shared__ unsigned short A_s[128 * 40];
    __shared__ unsigned short B_s[128 * 40];

    const unsigned short* Atab = (n_tile == 0) ? k_bf : v_bf;
    const unsigned short* Wtab; int wrow0;
    if (n_tile == 0)      { Wtab = Mk_bf; wrow0 = 0;   }
    else if (n_tile == 1) { Wtab = eW_bf; wrow0 = 0;   }
    else if (n_tile == 2) { Wtab = eW_bf; wrow0 = 128; }
    else if (n_tile == 3) { Wtab = aW_bf; wrow0 = 0;   }
    else                  { Wtab = aW_bf; wrow0 = 128; }

    if (tid < 128) {
        int pos = m_tile * 128 + tid;
        int it = item_seq[pos];
        int co = correct_seq[pos];
        idx_s[tid] = (n_tile == 0) ? it : (it + NITEM * co);
    }
    __syncthreads();

    int myrow[4], myc4[4], myidx[4];
    #pragma unroll
    for (int j = 0; j < 4; ++j) {
        int chunk = tid + 256 * j;
        myrow[j] = chunk >> 3;
        myc4[j]  = chunk & 7;
        myidx[j] = idx_s[myrow[j]];
    }

    f32x4 acc[2][8];
    #pragma unroll
    for (int mi = 0; mi < 2; ++mi)
        #pragma unroll
        for (int ni = 0; ni < 8; ++ni)
            acc[mi][ni] = (f32x4){0.f, 0.f, 0.f, 0.f};

    for (int bk = 0; bk < 8; ++bk) {
        int k0 = bk * 32;
        #pragma unroll
        for (int j = 0; j < 4; ++j) {
            int row = myrow[j], c4 = myc4[j];
            *(ushort4*)&A_s[row * 40 + c4 * 4] =
                *(const ushort4*)(Atab + (long)myidx[j] * DK + k0 + c4 * 4);
            *(ushort4*)&B_s[row * 40 + c4 * 4] =
                *(const ushort4*)(Wtab + (long)(wrow0 + row) * DK + k0 + c4 * 4);
        }
        __syncthreads();

        const int kq = lane >> 4;   // k-slot 0..3 (8 bf16 each)
        const int rr = lane & 15;
        bf16x8 af[2], bfr[8];
        #pragma unroll
        for (int mi = 0; mi < 2; ++mi)
            af[mi] = *(const bf16x8*)&A_s[(wv * 32 + mi * 16 + rr) * 40 + kq * 8];
        #pragma unroll
        for (int ni = 0; ni < 8; ++ni)
            bfr[ni] = *(const bf16x8*)&B_s[(ni * 16 + rr) * 40 + kq * 8];
        #pragma unroll
        for (int ni = 0; ni < 8; ++ni)
            #pragma unroll
            for (int mi = 0; mi < 2; ++mi)
                acc[mi][ni] = __builtin_amdgcn_mfma_f32_16x16x32_bf16(
                    af[mi], bfr[ni], acc[mi][ni], 0, 0, 0);
        __syncthreads();
    }

    // C/D layout: col = lane&15, row = (lane>>4)*4 + reg (m89-verified)
    const int rowbase = m_tile * 128 + wv * 32;
    const int cgrp = lane >> 4;
    const int cc   = lane & 15;

    if (n_tile == 0) {
        #pragma unroll
        for (int mi = 0; mi < 2; ++mi) {
            #pragma unroll
            for (int i = 0; i < 4; ++i) {
                float m = -1e30f;
                #pragma unroll
                for (int ni = 0; ni < 8; ++ni) m = fmaxf(m, acc[mi][ni][i]);
                m = fmaxf(m, __shfl_xor(m, 1));
                m = fmaxf(m, __shfl_xor(m, 2));
                m = fmaxf(m, __shfl_xor(m, 4));
                m = fmaxf(m, __shfl_xor(m, 8));
                float p[8]; float s = 0.f;
                #pragma unroll
                for (int ni = 0; ni < 8; ++ni) { p[ni] = __expf(acc[mi][ni][i] - m); s += p[ni]; }
                s += __shfl_xor(s, 1); s += __shfl_xor(s, 2);
                s += __shfl_xor(s, 4); s += __shfl_xor(s, 8);
                float inv = fast_rcp(s);
                int row = rowbase + mi * 16 + cgrp * 4 + i;
                #pragma unroll
                for (int ni = 0; ni < 8; ++ni)
                    Wout[(long)row * 128 + ni * 16 + cc] = f2bf(p[ni] * inv);
            }
        }
    } else {
        const bool is_e = (n_tile <= 2);
        const float* bias = is_e ? e_b : a_b;
        const int colbase = (is_e ? (n_tile - 1) : (n_tile - 3)) * 128;
        unsigned short* Out = is_e ? Eout : Aout;
        #pragma unroll
        for (int ni = 0; ni < 8; ++ni) {
            int colp = colbase + ni * 16 + cc;
            float bb = bias[colp];
            #pragma unroll
            for (int mi = 0; mi < 2; ++mi) {
                #pragma unroll
                for (int i = 0; i < 4; ++i) {
                    int row = rowbase + mi * 16 + cgrp * 4 + i;
                    float x = acc[mi][ni][i] + bb;
                    float v = is_e ? fast_sigmoid(x) : fast_tanh(x);
                    Out[(long)row * 256 + colp] = f2bf(v);
                }
            }
        }
    }
}

// ---------------------------------------------------------------------------
// K2: scan. Block = batch (256 blocks), 512 threads = 8 waves.
// thread (vo=tid>>6, kq=tid&63): owns k-cols 4kq..4kq+3, v in [16vo,16vo+16).
// Distance-2 prefetch (t-loop unrolled x2, named reg sets). Reduce: all waves
// write red[par][kq][wv] (pad 9), barrier, each wave reduces 8 col-groups via
// one ds_read_b128 + 3x shfl_xor tree; 1/8 lanes store ushort4.
// ---------------------------------------------------------------------------
__global__ __launch_bounds__(512, 1) void k2_scan(
    const float* __restrict__ Mv0,
    const unsigned short* __restrict__ Wws, const unsigned short* __restrict__ Ews,
    const unsigned short* __restrict__ Aws, unsigned short* __restrict__ Rws)
{
    const int b   = blockIdx.x;
    const int tid = threadIdx.x;
    const int kq  = tid & 63;       // also the lane id
    const int vo  = tid >> 6;       // wave id = v-octant

    __shared__ float4 red[2][64][9];   // [parity][kq][wv], pad 9 for banks

    f32x2 Ma[16], Mb[16];
    #pragma unroll
    for (int j = 0; j < 16; ++j) {
        float4 m4 = *(const float4*)(Mv0 + (vo * 16 + j) * DK + kq * 4);
        Ma[j] = (f32x2){m4.x, m4.y};
        Mb[j] = (f32x2){m4.z, m4.w};
    }

    const long pos0 = (long)b * T_SEQ;
    const unsigned int* Wd = (const unsigned int*)Wws;   // [pos][64 dwords]
    const int wslot = vo * 8 + (kq & 7);
    const int rcol  = vo * 8 + (kq >> 3);   // my reduce column-group

    // distance-2 prefetch pipeline, named sets (static indexing, rule #20)
    unsigned int wdA = Wd[(pos0 + 0) * 64 + wslot];
    uint2 edA = *(const uint2*)(Ews + (pos0 + 0) * 256 + kq * 4);
    uint2 adA = *(const uint2*)(Aws + (pos0 + 0) * 256 + kq * 4);
    unsigned int wdB = Wd[(pos0 + 1) * 64 + wslot];
    uint2 edB = *(const uint2*)(Ews + (pos0 + 1) * 256 + kq * 4);
    uint2 adB = *(const uint2*)(Aws + (pos0 + 1) * 256 + kq * 4);

#define K2_STEP(T, WD, ED, AD)                                                 \
    {                                                                          \
        const unsigned int wd = WD;                                            \
        const uint2 ed = ED, ad = AD;                                          \
        {   /* issue t+2 loads immediately: ~2 bodies of latency cover */      \
            long pn = pos0 + ((T) + 2 < T_SEQ ? (T) + 2 : T_SEQ - 1);          \
            WD = Wd[pn * 64 + wslot];                                          \
            ED = *(const uint2*)(Ews + pn * 256 + kq * 4);                     \
            AD = *(const uint2*)(Aws + pn * 256 + kq * 4);                     \
        }                                                                      \
        f32x2 ea = (f32x2){__uint_as_float(ed.x << 16),                        \
                           __uint_as_float(ed.x & 0xffff0000u)};               \
        f32x2 eb = (f32x2){__uint_as_float(ed.y << 16),                        \
                           __uint_as_float(ed.y & 0xffff0000u)};               \
        f32x2 aa = (f32x2){__uint_as_float(ad.x << 16),                        \
                           __uint_as_float(ad.x & 0xffff0000u)};               \
        f32x2 ab = (f32x2){__uint_as_float(ad.y << 16),                        \
                           __uint_as_float(ad.y & 0xffff0000u)};               \
        f32x2 nea = -ea, neb = -eb;                                            \
        f32x2 ra = (f32x2){0.f, 0.f}, rb = (f32x2){0.f, 0.f};                  \
        _Pragma("unroll")                                                      \
        for (int p = 0; p < 8; ++p) {                                          \
            unsigned int d = __builtin_amdgcn_readlane(wd, p);                 \
            float s0 = __uint_as_float(d << 16);                               \
            float s1 = __uint_as_float(d & 0xffff0000u);                       \
            {                                                                  \
                f32x2 s2 = (f32x2){s0, s0};                                    \
                f32x2 ma = Ma[2 * p], mb = Mb[2 * p];                          \
                ra = pk_fma(s2, ma, ra);                                       \
                rb = pk_fma(s2, mb, rb);                                       \
                f32x2 ta = pk_fma(nea, ma, aa);                                \
                f32x2 tb = pk_fma(neb, mb, ab);                                \
                Ma[2 * p] = pk_fma(s2, ta, ma);                                \
                Mb[2 * p] = pk_fma(s2, tb, mb);                                \
            }                                                                  \
            {                                                                  \
                f32x2 s2 = (f32x2){s1, s1};                                    \
                f32x2 ma = Ma[2 * p + 1], mb = Mb[2 * p + 1];                  \
                ra = pk_fma(s2, ma, ra);                                       \
                rb = pk_fma(s2, mb, rb);                                       \
                f32x2 ta = pk_fma(nea, ma, aa);                                \
                f32x2 tb = pk_fma(neb, mb, ab);                                \
                Ma[2 * p + 1] = pk_fma(s2, ta, ma);                            \
                Mb[2 * p + 1] = pk_fma(s2, tb, mb);                            \
            }                                                                  \
        }                                                                      \
        const int par = (T) & 1;                                               \
        red[par][kq][vo] = float4{ra.x, ra.y, rb.x, rb.y};                     \
        __syncthreads();                                                       \
        float4 r = red[par][rcol][kq & 7];                                     \
        r.x += __shfl_xor(r.x, 1); r.y += __shfl_xor(r.y, 1);                  \
        r.z += __shfl_xor(r.z, 1); r.w += __shfl_xor(r.w, 1);                  \
        r.x += __shfl_xor(r.x, 2); r.y += __shfl_xor(r.y, 2);                  \
        r.z += __shfl_xor(r.z, 2); r.w += __shfl_xor(r.w, 2);                  \
        r.x += __shfl_xor(r.x, 4); r.y += __shfl_xor(r.y, 4);                  \
        r.z += __shfl_xor(r.z, 4); r.w += __shfl_xor(r.w, 4);                  \
        if ((kq & 7) == 0) {                                                   \
            ushort4 o;                                                         \
            o.x = f2bf(r.x); o.y = f2bf(r.y);                                  \
            o.z = f2bf(r.z); o.w = f2bf(r.w);                                  \
            *(ushort4*)(Rws + (pos0 + (T)) * 256 + rcol * 4) = o;              \
        }                                                                      \
    }

    for (int t = 0; t < T_SEQ; t += 2) {
        K2_STEP(t,     wdA, edA, adA)
        K2_STEP(t + 1, wdB, edB, adB)
    }
#undef K2_STEP
}

// ---------------------------------------------------------------------------
// K3: f = tanh([reads | k] @ f_W^T + f_b). K=512.
// ---------------------------------------------------------------------------
__global__ __launch_bounds__(256) void k3_f(
    const int* __restrict__ item_seq,
    const unsigned short* __restrict__ k_bf,
    const unsigned short* __restrict__ fW_bf, const float* __restrict__ f_b,
    const unsigned short* __restrict__ Rws,
    unsigned short* __restrict__ Fout)
{
    const int m_tile = blockIdx.x;   // 0..1023
    const int nt  = blockIdx.y;      // 0..1
    const int tid = threadIdx.x;
    const int lane = tid & 63;
    const int wv   = tid >> 6;

    __shared__ int idx_s[128];
    __shared__ unsigned short A_s[128 * 40];
    __shared__ unsigned short B_s[128 * 40];

    if (tid < 128) idx_s[tid] = item_seq[m_tile * 128 + tid];
    __syncthreads();

    int myrow[4], myc4[4], myidx[4];
    #pragma unroll
    for (int j = 0; j < 4; ++j) {
        int chunk = tid + 256 * j;
        myrow[j] = chunk >> 3;
        myc4[j]  = chunk & 7;
        myidx[j] = idx_s[myrow[j]];
    }

    f32x4 acc[2][8];
    #pragma unroll
    for (int mi = 0; mi < 2; ++mi)
        #pragma unroll
        for (int ni = 0; ni < 8; ++ni)
            acc[mi][ni] = (f32x4){0.f, 0.f, 0.f, 0.f};

    for (int bk = 0; bk < 16; ++bk) {
        int k0 = bk * 32;
        #pragma unroll
        for (int j = 0; j < 4; ++j) {
            int row = myrow[j], c4 = myc4[j];
            ushort4 ap;
            if (k0 < 256) {
                long pos = (long)m_tile * 128 + row;
                ap = *(const ushort4*)(Rws + pos * 256 + k0 + c4 * 4);
            } else {
                ap = *(const ushort4*)(k_bf + (long)myidx[j] * DK + (k0 - 256) + c4 * 4);
            }
            *(ushort4*)&A_s[row * 40 + c4 * 4] = ap;
            *(ushort4*)&B_s[row * 40 + c4 * 4] =
                *(const ushort4*)(fW_bf + (long)(nt * 128 + row) * 512 + k0 + c4 * 4);
        }
        __syncthreads();

        const int kq = lane >> 4;
        const int rr = lane & 15;
        bf16x8 af[2], bfr[8];
        #pragma unroll
        for (int mi = 0; mi < 2; ++mi)
            af[mi] = *(const bf16x8*)&A_s[(wv * 32 + mi * 16 + rr) * 40 + kq * 8];
        #pragma unroll
        for (int ni = 0; ni < 8; ++ni)
            bfr[ni] = *(const bf16x8*)&B_s[(ni * 16 + rr) * 40 + kq * 8];
        #pragma unroll
        for (int ni = 0; ni < 8; ++ni)
            #pragma unroll
            for (int mi = 0; mi < 2; ++mi)
                acc[mi][ni] = __builtin_amdgcn_mfma_f32_16x16x32_bf16(
                    af[mi], bfr[ni], acc[mi][ni], 0, 0, 0);
        __syncthreads();
    }

    const int rowbase = m_tile * 128 + wv * 32;
    const int cgrp = lane >> 4;
    const int cc   = lane & 15;
    #pragma unroll
    for (int ni = 0; ni < 8; ++ni) {
        int colp = nt * 128 + ni * 16 + cc;
        float bb = f_b[colp];
        #pragma unroll
        for (int mi = 0; mi < 2; ++mi) {
            #pragma unroll
            for (int i = 0; i < 4; ++i) {
                int row = rowbase + mi * 16 + cgrp * 4 + i;
                Fout[(long)row * 256 + colp] = f2bf(fast_tanh(acc[mi][ni][i] + bb));
            }
        }
    }
}

// ---------------------------------------------------------------------------
// K4: predict = sigmoid(f . p_W + p_b). One wave per 64 consecutive rows.
// ---------------------------------------------------------------------------
__global__ __launch_bounds__(256) void k4_pred(
    const unsigned short* __restrict__ Fws,
    const float* __restrict__ p_W, const float* __restrict__ p_b,
    float* __restrict__ out)
{
    const int tid  = threadIdx.x;
    const int lane = tid & 63;
    const int wgid = blockIdx.x * 4 + (tid >> 6);   // 0..2047
    const float4 pw = *(const float4*)(p_W + lane * 4);
    const float pb = p_b[0];
    #pragma unroll 4
    for (int r = 0; r < 64; ++r) {
        long row = (long)wgid * 64 + r;
        ushort4 q = *(const ushort4*)(Fws + row * 256 + lane * 4);
        float partial = bf2f(q.x) * pw.x + bf2f(q.y) * pw.y
                      + bf2f(q.z) * pw.z + bf2f(q.w) * pw.w;
        #pragma unroll
        for (int off = 32; off >= 1; off >>= 1) partial += __shfl_xor(partial, off);
        if (lane == 0) out[row] = fast_sigmoid(partial + pb);
    }
}

// ---------------------------------------------------------------------------
extern "C" void kernel_launch(void* const* d_in, const int* in_sizes, int n_in,
                              void* d_out, int out_size, void* d_ws, size_t ws_size,
                              hipStream_t stream)
{
    const int*   item_seq    = (const int*)d_in[0];
    const int*   correct_seq = (const int*)d_in[1];
    const float* k_emb = (const float*)d_in[2];
    const float* v_emb = (const float*)d_in[3];
    const float* Mk    = (const float*)d_in[4];
    const float* Mv0   = (const float*)d_in[5];
    const float* e_W   = (const float*)d_in[6];
    const float* e_b   = (const float*)d_in[7];
    const float* a_W   = (const float*)d_in[8];
    const float* a_b   = (const float*)d_in[9];
    const float* f_W   = (const float*)d_in[10];
    const float* f_b   = (const float*)d_in[11];
    const float* p_W   = (const float*)d_in[12];
    const float* p_b   = (const float*)d_in[13];
    float* out = (float*)d_out;

    // ws layout (bytes):
    //   [0,   32M)  Wws  w bf16 [BT][128]     (k3 tables re-use this after k2)
    //   [32M, 96M)  Ews  e bf16 [BT][256]     (aliased by f = k3 output)
    //   [96M, 160M) Aws  a bf16 [BT][256]
    //   [160M,224M) Rws  reads bf16 [BT][256] (k1 bf16 tables live here pre-k2)
    char* ws = (char*)d_ws;
    unsigned short* Wws = (unsigned short*)(ws);
    unsigned short* Ews = (unsigned short*)(ws + 33554432ll);
    unsigned short* Aws = (unsigned short*)(ws + 100663296ll);
    unsigned short* Rws = (unsigned short*)(ws + 167772160ll);

    // k1-phase bf16 tables, parked in the (still dead) Rws region
    unsigned short* kA_bf = Rws;                 // 512000
    unsigned short* v_bf  = Rws + 512000;        // 1024000
    unsigned short* Mk_bf = Rws + 1536000;       // 32768
    unsigned short* eW_bf = Rws + 1568768;       // 65536
    unsigned short* aW_bf = Rws + 1634304;       // 65536
    // k3-phase bf16 tables, parked in the (dead after k2) Wws region
    unsigned short* k3_bf = Wws;                 // 512000
    unsigned short* fW_bf = Wws + 512000;        // 131072

    k0_cvt<<<dim3(1000, 5), dim3(256), 0, stream>>>(
        k_emb, v_emb, Mk, e_W, a_W,
        kA_bf, v_bf, Mk_bf, eW_bf, aW_bf,
        512000, 1024000, 32768, 65536, 65536);

    k1_wea<<<dim3(1024, 5), dim3(256), 0, stream>>>(
        item_seq, correct_seq, kA_bf, v_bf, Mk_bf, eW_bf, e_b, aW_bf, a_b,
        Wws, Ews, Aws);

    k2_scan<<<dim3(256), dim3(512), 0, stream>>>(Mv0, Wws, Ews, Aws, Rws);

    k0_cvt<<<dim3(500, 2), dim3(256), 0, stream>>>(
        k_emb, f_W, nullptr, nullptr, nullptr,
        k3_bf, fW_bf, nullptr, nullptr, nullptr,
        512000, 131072, 0, 0, 0);

    k3_f<<<dim3(1024, 2), dim3(256), 0, stream>>>(
        item_seq, k3_bf, fW_bf, f_b, Rws, Ews /* f overwrites e */);

    k4_pred<<<dim3(512), dim3(256), 0, stream>>>(Ews, p_W, p_b, out);
}

// Round 4
// 518.557 us; speedup vs baseline: 1.3255x; 1.3255x over previous
//
#include <hip/hip_runtime.h>
#include <hip/hip_bf16.h>

// DKVMN fused pipeline for MI355X (gfx950)
// B=256, T=512, DIM_KEY=256, DIM_VALUE=128, NUM_ITEM=2000
// k0_cvt : f32 tables -> bf16 tables in ws
// k1_wea : gather + [Mk|e_W|a_W] GEMM (bf16 MFMA) + softmax/sigmoid/tanh -> ws
// k2_scan: per-batch scan; M state in VGPRs, 8 waves split v; distance-2
//          prefetch; chunked deferred reduce (8 steps/chunk, conflict-free
//          contiguous LDS, 2 barriers per 8 steps)
// k3_f   : [reads|k] @ f_W^T GEMM (bf16 MFMA) + tanh -> ws (aliases e)
// k4_pred: sigmoid(f . p_W + p_b) -> d_out (f32)

#define T_SEQ 512
#define DK    256
#define DV    128
#define NITEM 2000
#define BT    131072   // 256*512

typedef __attribute__((ext_vector_type(8))) short bf16x8;
typedef __attribute__((ext_vector_type(4))) float f32x4;
typedef __attribute__((ext_vector_type(2))) float f32x2;

__device__ __forceinline__ float bf2f(unsigned short u) {
    return __uint_as_float(((unsigned int)u) << 16);
}
__device__ __forceinline__ unsigned short f2bf(float x) {   // RNE f32->bf16
    unsigned int u = __float_as_uint(x);
    return (unsigned short)((u + 0x7fffu + ((u >> 16) & 1u)) >> 16);
}
__device__ __forceinline__ float fast_rcp(float x) { return __builtin_amdgcn_rcpf(x); }
__device__ __forceinline__ float fast_sigmoid(float x) { return fast_rcp(1.f + __expf(-x)); }
__device__ __forceinline__ float fast_tanh(float x) {
    float t = __expf(2.f * x);
    return (t - 1.f) * fast_rcp(t + 1.f);
}

// 2xf32 fma helper. NOTE (R2 post-mortem): v_pk_fma_f32 is throughput-neutral
// on CDNA4 (157.3 TF peak == scalar fma rate); this exists only for brevity.
__device__ __forceinline__ f32x2 pk_fma(f32x2 a, f32x2 b, f32x2 c) {
#if __has_builtin(__builtin_elementwise_fma)
    return __builtin_elementwise_fma(a, b, c);
#else
    f32x2 d; d.x = fmaf(a.x, b.x, c.x); d.y = fmaf(a.y, b.y, c.y); return d;
#endif
}

// ---------------------------------------------------------------------------
// k0: f32 -> bf16 table conversion (up to 5 tables per launch, y = table id)
// ---------------------------------------------------------------------------
__global__ __launch_bounds__(256) void k0_cvt(
    const float* __restrict__ s0, const float* __restrict__ s1,
    const float* __restrict__ s2, const float* __restrict__ s3,
    const float* __restrict__ s4,
    unsigned short* __restrict__ d0, unsigned short* __restrict__ d1,
    unsigned short* __restrict__ d2, unsigned short* __restrict__ d3,
    unsigned short* __restrict__ d4,
    int n0, int n1, int n2, int n3, int n4)
{
    const float* s; unsigned short* d; int n;
    switch (blockIdx.y) {
        case 0:  s = s0; d = d0; n = n0; break;
        case 1:  s = s1; d = d1; n = n1; break;
        case 2:  s = s2; d = d2; n = n2; break;
        case 3:  s = s3; d = d3; n = n3; break;
        default: s = s4; d = d4; n = n4; break;
    }
    int i4 = (blockIdx.x * 256 + threadIdx.x) * 4;
    if (i4 < n) {
        float4 v = *(const float4*)(s + i4);
        ushort4 o;
        o.x = f2bf(v.x); o.y = f2bf(v.y); o.z = f2bf(v.z); o.w = f2bf(v.w);
        *(ushort4*)(d + i4) = o;
    }
}

// ---------------------------------------------------------------------------
// K1: 128 rows x 128 cols per block, 4 waves stacked by rows.
// ---------------------------------------------------------------------------
__global__ __launch_bounds__(256) void k1_wea(
    const int* __restrict__ item_seq, const int* __restrict__ correct_seq,
    const unsigned short* __restrict__ k_bf, const unsigned short* __restrict__ v_bf,
    const unsigned short* __restrict__ Mk_bf,
    const unsigned short* __restrict__ eW_bf, const float* __restrict__ e_b,
    const unsigned short* __restrict__ aW_bf, const float* __restrict__ a_b,
    unsigned short* __restrict__ Wout, unsigned short* __restrict__ Eout,
    unsigned short* __restrict__ Aout)
{
    const int m_tile = blockIdx.x;   // 0..1023
    const int n_tile = blockIdx.y;   // 0..4
    const int tid  = threadIdx.x;
    const int lane = tid & 63;
    const int wv   = tid >> 6;

    __shared__ int idx_s[128];
    __shared__ unsigned short A_s[128 * 40];
    __shared__ unsigned short B_s[128 * 40];

    const unsigned short* Atab = (n_tile == 0) ? k_bf : v_bf;
    const unsigned short* Wtab; int wrow0;
    if (n_tile == 0)      { Wtab = Mk_bf; wrow0 = 0;   }
    else if (n_tile == 1) { Wtab = eW_bf; wrow0 = 0;   }
    else if (n_tile == 2) { Wtab = eW_bf; wrow0 = 128; }
    else if (n_tile == 3) { Wtab = aW_bf; wrow0 = 0;   }
    else                  { Wtab = aW_bf; wrow0 = 128; }

    if (tid < 128) {
        int pos = m_tile * 128 + tid;
        int it = item_seq[pos];
        int co = correct_seq[pos];
        idx_s[tid] = (n_tile == 0) ? it : (it + NITEM * co);
    }
    __syncthreads();

    int myrow[4], myc4[4], myidx[4];
    #pragma unroll
    for (int j = 0; j < 4; ++j) {
        int chunk = tid + 256 * j;
        myrow[j] = chunk >> 3;
        myc4[j]  = chunk & 7;
        myidx[j] = idx_s[myrow[j]];
    }

    f32x4 acc[2][8];
    #pragma unroll
    for (int mi = 0; mi < 2; ++mi)
        #pragma unroll
        for (int ni = 0; ni < 8; ++ni)
            acc[mi][ni] = (f32x4){0.f, 0.f, 0.f, 0.f};

    for (int bk = 0; bk < 8; ++bk) {
        int k0 = bk * 32;
        #pragma unroll
        for (int j = 0; j < 4; ++j) {
            int row = myrow[j], c4 = myc4[j];
            *(ushort4*)&A_s[row * 40 + c4 * 4] =
                *(const ushort4*)(Atab + (long)myidx[j] * DK + k0 + c4 * 4);
            *(ushort4*)&B_s[row * 40 + c4 * 4] =
                *(const ushort4*)(Wtab + (long)(wrow0 + row) * DK + k0 + c4 * 4);
        }
        __syncthreads();

        const int kq = lane >> 4;   // k-slot 0..3 (8 bf16 each)
        const int rr = lane & 15;
        bf16x8 af[2], bfr[8];
        #pragma unroll
        for (int mi = 0; mi < 2; ++mi)
            af[mi] = *(const bf16x8*)&A_s[(wv * 32 + mi * 16 + rr) * 40 + kq * 8];
        #pragma unroll
        for (int ni = 0; ni < 8; ++ni)
            bfr[ni] = *(const bf16x8*)&B_s[(ni * 16 + rr) * 40 + kq * 8];
        #pragma unroll
        for (int ni = 0; ni < 8; ++ni)
            #pragma unroll
            for (int mi = 0; mi < 2; ++mi)
                acc[mi][ni] = __builtin_amdgcn_mfma_f32_16x16x32_bf16(
                    af[mi], bfr[ni], acc[mi][ni], 0, 0, 0);
        __syncthreads();
    }

    // C/D layout: col = lane&15, row = (lane>>4)*4 + reg (m89-verified)
    const int rowbase = m_tile * 128 + wv * 32;
    const int cgrp = lane >> 4;
    const int cc   = lane & 15;

    if (n_tile == 0) {
        #pragma unroll
        for (int mi = 0; mi < 2; ++mi) {
            #pragma unroll
            for (int i = 0; i < 4; ++i) {
                float m = -1e30f;
                #pragma unroll
                for (int ni = 0; ni < 8; ++ni) m = fmaxf(m, acc[mi][ni][i]);
                m = fmaxf(m, __shfl_xor(m, 1));
                m = fmaxf(m, __shfl_xor(m, 2));
                m = fmaxf(m, __shfl_xor(m, 4));
                m = fmaxf(m, __shfl_xor(m, 8));
                float p[8]; float s = 0.f;
                #pragma unroll
                for (int ni = 0; ni < 8; ++ni) { p[ni] = __expf(acc[mi][ni][i] - m); s += p[ni]; }
                s += __shfl_xor(s, 1); s += __shfl_xor(s, 2);
                s += __shfl_xor(s, 4); s += __shfl_xor(s, 8);
                float inv = fast_rcp(s);
                int row = rowbase + mi * 16 + cgrp * 4 + i;
                #pragma unroll
                for (int ni = 0; ni < 8; ++ni)
                    Wout[(long)row * 128 + ni * 16 + cc] = f2bf(p[ni] * inv);
            }
        }
    } else {
        const bool is_e = (n_tile <= 2);
        const float* bias = is_e ? e_b : a_b;
        const int colbase = (is_e ? (n_tile - 1) : (n_tile - 3)) * 128;
        unsigned short* Out = is_e ? Eout : Aout;
        #pragma unroll
        for (int ni = 0; ni < 8; ++ni) {
            int colp = colbase + ni * 16 + cc;
            float bb = bias[colp];
            #pragma unroll
            for (int mi = 0; mi < 2; ++mi) {
                #pragma unroll
                for (int i = 0; i < 4; ++i) {
                    int row = rowbase + mi * 16 + cgrp * 4 + i;
                    float x = acc[mi][ni][i] + bb;
                    float v = is_e ? fast_sigmoid(x) : fast_tanh(x);
                    Out[(long)row * 256 + colp] = f2bf(v);
                }
            }
        }
    }
}

// ---------------------------------------------------------------------------
// K2: scan. Block = batch (256 blocks), 512 threads = 8 waves.
// thread (vo=tid>>6, kq=tid&63): owns k-cols 4kq..4kq+3, v in [16vo,16vo+16).
// Distance-2 prefetch (t-loop unrolled, named reg sets A/B).
// Reduce (R3 post-mortem fix): per step each wave does ONE contiguous
// ds_write_b128 part[t&7][vo][kq] (conflict-free). Every 8 steps: barrier;
// wave w sums slot w over the 8 waves (8 contiguous ds_read_b128 + adds),
// stores 512B coalesced to Rws; barrier. 0.25 barriers/step, zero shfl.
// ---------------------------------------------------------------------------
__global__ __launch_bounds__(512, 1) void k2_scan(
    const float* __restrict__ Mv0,
    const unsigned short* __restrict__ Wws, const unsigned short* __restrict__ Ews,
    const unsigned short* __restrict__ Aws, unsigned short* __restrict__ Rws)
{
    const int b   = blockIdx.x;
    const int tid = threadIdx.x;
    const int kq  = tid & 63;       // lane id = k-quad
    const int vo  = tid >> 6;       // wave id = v-octant

    __shared__ float4 part[8][8][64];   // [t&7][wave][kq] = 64 KiB, conflict-free

    f32x2 Ma[16], Mb[16];
    #pragma unroll
    for (int j = 0; j < 16; ++j) {
        float4 m4 = *(const float4*)(Mv0 + (vo * 16 + j) * DK + kq * 4);
        Ma[j] = (f32x2){m4.x, m4.y};
        Mb[j] = (f32x2){m4.z, m4.w};
    }

    const long pos0 = (long)b * T_SEQ;
    const unsigned int* Wd = (const unsigned int*)Wws;   // [pos][64 dwords]
    const int wslot = vo * 8 + (kq & 7);

    // distance-2 prefetch pipeline, named sets (static indexing, rule #20)
    unsigned int wdA = Wd[(pos0 + 0) * 64 + wslot];
    uint2 edA = *(const uint2*)(Ews + (pos0 + 0) * 256 + kq * 4);
    uint2 adA = *(const uint2*)(Aws + (pos0 + 0) * 256 + kq * 4);
    unsigned int wdB = Wd[(pos0 + 1) * 64 + wslot];
    uint2 edB = *(const uint2*)(Ews + (pos0 + 1) * 256 + kq * 4);
    uint2 adB = *(const uint2*)(Aws + (pos0 + 1) * 256 + kq * 4);

#define K2_STEP(T, SLOT, WD, ED, AD)                                           \
    {                                                                          \
        const unsigned int wd = WD;                                            \
        const uint2 ed = ED, ad = AD;                                          \
        {   /* issue t+2 loads immediately: ~2 bodies of latency cover */      \
            long pn = pos0 + ((T) + 2 < T_SEQ ? (T) + 2 : T_SEQ - 1);          \
            WD = Wd[pn * 64 + wslot];                                          \
            ED = *(const uint2*)(Ews + pn * 256 + kq * 4);                     \
            AD = *(const uint2*)(Aws + pn * 256 + kq * 4);                     \
        }                                                                      \
        f32x2 ea = (f32x2){__uint_as_float(ed.x << 16),                        \
                           __uint_as_float(ed.x & 0xffff0000u)};               \
        f32x2 eb = (f32x2){__uint_as_float(ed.y << 16),                        \
                           __uint_as_float(ed.y & 0xffff0000u)};               \
        f32x2 aa = (f32x2){__uint_as_float(ad.x << 16),                        \
                           __uint_as_float(ad.x & 0xffff0000u)};               \
        f32x2 ab = (f32x2){__uint_as_float(ad.y << 16),                        \
                           __uint_as_float(ad.y & 0xffff0000u)};               \
        f32x2 nea = -ea, neb = -eb;                                            \
        f32x2 ra = (f32x2){0.f, 0.f}, rb = (f32x2){0.f, 0.f};                  \
        _Pragma("unroll")                                                      \
        for (int p = 0; p < 8; ++p) {                                          \
            unsigned int d = __builtin_amdgcn_readlane(wd, p);                 \
            float s0 = __uint_as_float(d << 16);                               \
            float s1 = __uint_as_float(d & 0xffff0000u);                       \
            {                                                                  \
                f32x2 s2 = (f32x2){s0, s0};                                    \
                f32x2 ma = Ma[2 * p], mb = Mb[2 * p];                          \
                ra = pk_fma(s2, ma, ra);                                       \
                rb = pk_fma(s2, mb, rb);                                       \
                f32x2 ta = pk_fma(nea, ma, aa);                                \
                f32x2 tb = pk_fma(neb, mb, ab);                                \
                Ma[2 * p] = pk_fma(s2, ta, ma);                                \
                Mb[2 * p] = pk_fma(s2, tb, mb);                                \
            }                                                                  \
            {                                                                  \
                f32x2 s2 = (f32x2){s1, s1};                                    \
                f32x2 ma = Ma[2 * p + 1], mb = Mb[2 * p + 1];                  \
                ra = pk_fma(s2, ma, ra);                                       \
                rb = pk_fma(s2, mb, rb);                                       \
                f32x2 ta = pk_fma(nea, ma, aa);                                \
                f32x2 tb = pk_fma(neb, mb, ab);                                \
                Ma[2 * p + 1] = pk_fma(s2, ta, ma);                            \
                Mb[2 * p + 1] = pk_fma(s2, tb, mb);                            \
            }                                                                  \
        }                                                                      \
        part[SLOT][vo][kq] = float4{ra.x, ra.y, rb.x, rb.y};                   \
    }

    for (int tc = 0; tc < T_SEQ; tc += 8) {
        K2_STEP(tc + 0, 0, wdA, edA, adA)
        K2_STEP(tc + 1, 1, wdB, edB, adB)
        K2_STEP(tc + 2, 2, wdA, edA, adA)
        K2_STEP(tc + 3, 3, wdB, edB, adB)
        K2_STEP(tc + 4, 4, wdA, edA, adA)
        K2_STEP(tc + 5, 5, wdB, edB, adB)
        K2_STEP(tc + 6, 6, wdA, edA, adA)
        K2_STEP(tc + 7, 7, wdB, edB, adB)
        __syncthreads();
        {   // wave vo reduces time-slot vo: sum over the 8 waves' partials
            float4 s = part[vo][0][kq];
            #pragma unroll
            for (int w2 = 1; w2 < 8; ++w2) {
                float4 r = part[vo][w2][kq];
                s.x += r.x; s.y += r.y; s.z += r.z; s.w += r.w;
            }
            ushort4 o;
            o.x = f2bf(s.x); o.y = f2bf(s.y); o.z = f2bf(s.z); o.w = f2bf(s.w);
            *(ushort4*)(Rws + (pos0 + tc + vo) * 256 + kq * 4) = o;
        }
        __syncthreads();
    }
#undef K2_STEP
}

// ---------------------------------------------------------------------------
// K3: f = tanh([reads | k] @ f_W^T + f_b). K=512.
// ---------------------------------------------------------------------------
__global__ __launch_bounds__(256) void k3_f(
    const int* __restrict__ item_seq,
    const unsigned short* __restrict__ k_bf,
    const unsigned short* __restrict__ fW_bf, const float* __restrict__ f_b,
    const unsigned short* __restrict__ Rws,
    unsigned short* __restrict__ Fout)
{
    const int m_tile = blockIdx.x;   // 0..1023
    const int nt  = blockIdx.y;      // 0..1
    const int tid = threadIdx.x;
    const int lane = tid & 63;
    const int wv   = tid >> 6;

    __shared__ int idx_s[128];
    __shared__ unsigned short A_s[128 * 40];
    __shared__ unsigned short B_s[128 * 40];

    if (tid < 128) idx_s[tid] = item_seq[m_tile * 128 + tid];
    __syncthreads();

    int myrow[4], myc4[4], myidx[4];
    #pragma unroll
    for (int j = 0; j < 4; ++j) {
        int chunk = tid + 256 * j;
        myrow[j] = chunk >> 3;
        myc4[j]  = chunk & 7;
        myidx[j] = idx_s[myrow[j]];
    }

    f32x4 acc[2][8];
    #pragma unroll
    for (int mi = 0; mi < 2; ++mi)
        #pragma unroll
        for (int ni = 0; ni < 8; ++ni)
            acc[mi][ni] = (f32x4){0.f, 0.f, 0.f, 0.f};

    for (int bk = 0; bk < 16; ++bk) {
        int k0 = bk * 32;
        #pragma unroll
        for (int j = 0; j < 4; ++j) {
            int row = myrow[j], c4 = myc4[j];
            ushort4 ap;
            if (k0 < 256) {
                long pos = (long)m_tile * 128 + row;
                ap = *(const ushort4*)(Rws + pos * 256 + k0 + c4 * 4);
            } else {
                ap = *(const ushort4*)(k_bf + (long)myidx[j] * DK + (k0 - 256) + c4 * 4);
            }
            *(ushort4*)&A_s[row * 40 + c4 * 4] = ap;
            *(ushort4*)&B_s[row * 40 + c4 * 4] =
                *(const ushort4*)(fW_bf + (long)(nt * 128 + row) * 512 + k0 + c4 * 4);
        }
        __syncthreads();

        const int kq = lane >> 4;
        const int rr = lane & 15;
        bf16x8 af[2], bfr[8];
        #pragma unroll
        for (int mi = 0; mi < 2; ++mi)
            af[mi] = *(const bf16x8*)&A_s[(wv * 32 + mi * 16 + rr) * 40 + kq * 8];
        #pragma unroll
        for (int ni = 0; ni < 8; ++ni)
            bfr[ni] = *(const bf16x8*)&B_s[(ni * 16 + rr) * 40 + kq * 8];
        #pragma unroll
        for (int ni = 0; ni < 8; ++ni)
            #pragma unroll
            for (int mi = 0; mi < 2; ++mi)
                acc[mi][ni] = __builtin_amdgcn_mfma_f32_16x16x32_bf16(
                    af[mi], bfr[ni], acc[mi][ni], 0, 0, 0);
        __syncthreads();
    }

    const int rowbase = m_tile * 128 + wv * 32;
    const int cgrp = lane >> 4;
    const int cc   = lane & 15;
    #pragma unroll
    for (int ni = 0; ni < 8; ++ni) {
        int colp = nt * 128 + ni * 16 + cc;
        float bb = f_b[colp];
        #pragma unroll
        for (int mi = 0; mi < 2; ++mi) {
            #pragma unroll
            for (int i = 0; i < 4; ++i) {
                int row = rowbase + mi * 16 + cgrp * 4 + i;
                Fout[(long)row * 256 + colp] = f2bf(fast_tanh(acc[mi][ni][i] + bb));
            }
        }
    }
}

// ---------------------------------------------------------------------------
// K4: predict = sigmoid(f . p_W + p_b). One wave per 64 consecutive rows.
// ---------------------------------------------------------------------------
__global__ __launch_bounds__(256) void k4_pred(
    const unsigned short* __restrict__ Fws,
    const float* __restrict__ p_W, const float* __restrict__ p_b,
    float* __restrict__ out)
{
    const int tid  = threadIdx.x;
    const int lane = tid & 63;
    const int wgid = blockIdx.x * 4 + (tid >> 6);   // 0..2047
    const float4 pw = *(const float4*)(p_W + lane * 4);
    const float pb = p_b[0];
    #pragma unroll 4
    for (int r = 0; r < 64; ++r) {
        long row = (long)wgid * 64 + r;
        ushort4 q = *(const ushort4*)(Fws + row * 256 + lane * 4);
        float partial = bf2f(q.x) * pw.x + bf2f(q.y) * pw.y
                      + bf2f(q.z) * pw.z + bf2f(q.w) * pw.w;
        #pragma unroll
        for (int off = 32; off >= 1; off >>= 1) partial += __shfl_xor(partial, off);
        if (lane == 0) out[row] = fast_sigmoid(partial + pb);
    }
}

// ---------------------------------------------------------------------------
extern "C" void kernel_launch(void* const* d_in, const int* in_sizes, int n_in,
                              void* d_out, int out_size, void* d_ws, size_t ws_size,
                              hipStream_t stream)
{
    const int*   item_seq    = (const int*)d_in[0];
    const int*   correct_seq = (const int*)d_in[1];
    const float* k_emb = (const float*)d_in[2];
    const float* v_emb = (const float*)d_in[3];
    const float* Mk    = (const float*)d_in[4];
    const float* Mv0   = (const float*)d_in[5];
    const float* e_W   = (const float*)d_in[6];
    const float* e_b   = (const float*)d_in[7];
    const float* a_W   = (const float*)d_in[8];
    const float* a_b   = (const float*)d_in[9];
    const float* f_W   = (const float*)d_in[10];
    const float* f_b   = (const float*)d_in[11];
    const float* p_W   = (const float*)d_in[12];
    const float* p_b   = (const float*)d_in[13];
    float* out = (float*)d_out;

    // ws layout (bytes):
    //   [0,   32M)  Wws  w bf16 [BT][128]     (k3 tables re-use this after k2)
    //   [32M, 96M)  Ews  e bf16 [BT][256]     (aliased by f = k3 output)
    //   [96M, 160M) Aws  a bf16 [BT][256]
    //   [160M,224M) Rws  reads bf16 [BT][256] (k1 bf16 tables live here pre-k2)
    char* ws = (char*)d_ws;
    unsigned short* Wws = (unsigned short*)(ws);
    unsigned short* Ews = (unsigned short*)(ws + 33554432ll);
    unsigned short* Aws = (unsigned short*)(ws + 100663296ll);
    unsigned short* Rws = (unsigned short*)(ws + 167772160ll);

    // k1-phase bf16 tables, parked in the (still dead) Rws region
    unsigned short* kA_bf = Rws;                 // 512000
    unsigned short* v_bf  = Rws + 512000;        // 1024000
    unsigned short* Mk_bf = Rws + 1536000;       // 32768
    unsigned short* eW_bf = Rws + 1568768;       // 65536
    unsigned short* aW_bf = Rws + 1634304;       // 65536
    // k3-phase bf16 tables, parked in the (dead after k2) Wws region
    unsigned short* k3_bf = Wws;                 // 512000
    unsigned short* fW_bf = Wws + 512000;        // 131072

    k0_cvt<<<dim3(1000, 5), dim3(256), 0, stream>>>(
        k_emb, v_emb, Mk, e_W, a_W,
        kA_bf, v_bf, Mk_bf, eW_bf, aW_bf,
        512000, 1024000, 32768, 65536, 65536);

    k1_wea<<<dim3(1024, 5), dim3(256), 0, stream>>>(
        item_seq, correct_seq, kA_bf, v_bf, Mk_bf, eW_bf, e_b, aW_bf, a_b,
        Wws, Ews, Aws);

    k2_scan<<<dim3(256), dim3(512), 0, stream>>>(Mv0, Wws, Ews, Aws, Rws);

    k0_cvt<<<dim3(500, 2), dim3(256), 0, stream>>>(
        k_emb, f_W, nullptr, nullptr, nullptr,
        k3_bf, fW_bf, nullptr, nullptr, nullptr,
        512000, 131072, 0, 0, 0);

    k3_f<<<dim3(1024, 2), dim3(256), 0, stream>>>(
        item_seq, k3_bf, fW_bf, f_b, Rws, Ews /* f overwrites e */);

    k4_pred<<<dim3(512), dim3(256), 0, stream>>>(Ews, p_W, p_b, out);
}